// Round 1
// baseline (1298.500 us; speedup 1.0000x reference)
//
#include <hip/hip_runtime.h>
#include <math.h>

// Problem constants (Llama-70B-style GQA decode)
#define BATCH 32
#define NHEAD 32
#define HDIM 128
#define NKVH 8
#define NGRP 4            // NHEAD / NKVH
#define BLKSZ 16
#define MAXBLK 256
#define MAXS 4096
#define NUMBLOCKS (BATCH * MAXBLK)
#define NCHUNK 8
#define CHUNK 512         // MAXS / NCHUNK
#define QK_SCALE 0.088388347648318447f   // 1/sqrt(128)

// ---------------------------------------------------------------------------
// Kernel 1: per-(chunk, kvhead, batch) partial attention (flash-decoding).
// Block = 256 threads = 4 waves; wave w handles 128 positions of the chunk.
// Writes partial O (G x D), running max m, running sumexp l into workspace.
// The new token's K/V (position L-1) is substituted from the key/value inputs
// instead of the (stale) cache -- the reference's cache write only lands there.
// ---------------------------------------------------------------------------
__global__ __launch_bounds__(256) void attn_partial(
    const float* __restrict__ q,        // (B, H*D)
    const float* __restrict__ knew,     // (B, HKV*D)
    const float* __restrict__ vnew,     // (B, HKV*D)
    const float* __restrict__ cache,    // (2, NUMBLOCKS, BS, HKV, D)
    const int*   __restrict__ btab,     // (B, MB)
    const int*   __restrict__ seq_lens, // (B,)
    float* __restrict__ pO,             // (B,HKV,G,NCHUNK,D)
    float* __restrict__ pM,             // (B,HKV,G,NCHUNK)
    float* __restrict__ pL)             // (B,HKV,G,NCHUNK)
{
    const int c   = blockIdx.x;
    const int kvh = blockIdx.y;
    const int b   = blockIdx.z;
    const int L   = seq_lens[b];
    const int p0  = c * CHUNK;
    if (p0 >= L) return;                       // chunk entirely past seq end
    const int pend = min(p0 + CHUNK, L);

    const int tid  = threadIdx.x;
    const int wave = tid >> 6;
    const int lane = tid & 63;
    const int half = lane >> 5;                // which position of the pair
    const int l32  = lane & 31;                // float4 slot within the row

    __shared__ float sc[NGRP][CHUNK];          // logits -> exp(p)   (8 KB)
    __shared__ float qs[NGRP * HDIM];          // the 4 query heads  (2 KB)
    __shared__ float red[4][NGRP][HDIM];       // cross-wave reduce  (8 KB)
    __shared__ int   bts[CHUNK / BLKSZ];       // block ids          (128 B)

    // stage q (heads g*NKVH + kvh) and this chunk's block-table entries
    for (int idx = tid; idx < NGRP * HDIM; idx += 256) {
        int g = idx >> 7, d = idx & (HDIM - 1);
        qs[idx] = q[(size_t)b * NHEAD * HDIM + (g * NKVH + kvh) * HDIM + d];
    }
    if (tid < CHUNK / BLKSZ)
        bts[tid] = btab[b * MAXBLK + p0 / BLKSZ + tid];
    __syncthreads();

    float4 qr0 = *(const float4*)&qs[0 * HDIM + l32 * 4];
    float4 qr1 = *(const float4*)&qs[1 * HDIM + l32 * 4];
    float4 qr2 = *(const float4*)&qs[2 * HDIM + l32 * 4];
    float4 qr3 = *(const float4*)&qs[3 * HDIM + l32 * 4];

    const int wbase = p0 + wave * 128;
    const float* newkrow = knew + (size_t)(b * NKVH + kvh) * HDIM;
    const float* newvrow = vnew + (size_t)(b * NKVH + kvh) * HDIM;

    // ---- QK^T pass: each half-wave computes one position per iteration ----
    for (int it = 0; it < 64; ++it) {
        int pos = wbase + it * 2 + half;
        int idx = pos - p0;
        if (pos < pend) {
            const float* krow;
            if (pos == L - 1) {
                krow = newkrow;
            } else {
                int bid = bts[idx >> 4];
                krow = cache + (size_t)((bid * BLKSZ + (pos & 15)) * NKVH + kvh) * HDIM;
            }
            float4 k4 = *(const float4*)(krow + l32 * 4);
            float s0 = k4.x * qr0.x + k4.y * qr0.y + k4.z * qr0.z + k4.w * qr0.w;
            float s1 = k4.x * qr1.x + k4.y * qr1.y + k4.z * qr1.z + k4.w * qr1.w;
            float s2 = k4.x * qr2.x + k4.y * qr2.y + k4.z * qr2.z + k4.w * qr2.w;
            float s3 = k4.x * qr3.x + k4.y * qr3.y + k4.z * qr3.z + k4.w * qr3.w;
            #pragma unroll
            for (int m = 16; m >= 1; m >>= 1) {
                s0 += __shfl_xor(s0, m, 32);
                s1 += __shfl_xor(s1, m, 32);
                s2 += __shfl_xor(s2, m, 32);
                s3 += __shfl_xor(s3, m, 32);
            }
            if (l32 == 0) {
                sc[0][idx] = s0 * QK_SCALE;
                sc[1][idx] = s1 * QK_SCALE;
                sc[2][idx] = s2 * QK_SCALE;
                sc[3][idx] = s3 * QK_SCALE;
            }
        } else {
            if (l32 == 0) {
                sc[0][idx] = -1e30f;
                sc[1][idx] = -1e30f;
                sc[2][idx] = -1e30f;
                sc[3][idx] = -1e30f;
            }
        }
    }
    __syncthreads();

    // ---- per-head softmax stats: wave g owns head g ----
    {
        const int g = wave;
        float m = -1e30f;
        for (int i = lane; i < CHUNK; i += 64) m = fmaxf(m, sc[g][i]);
        #pragma unroll
        for (int mm = 32; mm >= 1; mm >>= 1) m = fmaxf(m, __shfl_xor(m, mm, 64));
        float lsum = 0.f;
        for (int i = lane; i < CHUNK; i += 64) {
            float e = __expf(sc[g][i] - m);   // invalid entries -> exp(-1e30)=0
            sc[g][i] = e;
            lsum += e;
        }
        #pragma unroll
        for (int mm = 32; mm >= 1; mm >>= 1) lsum += __shfl_xor(lsum, mm, 64);
        if (lane == 0) {
            int base = ((b * NKVH + kvh) * NGRP + g) * NCHUNK + c;
            pM[base] = m;
            pL[base] = lsum;
        }
    }
    __syncthreads();

    // ---- P*V pass ----
    const float* vcache = cache + (size_t)NUMBLOCKS * BLKSZ * NKVH * HDIM;
    float4 a0 = {0, 0, 0, 0}, a1 = {0, 0, 0, 0}, a2 = {0, 0, 0, 0}, a3 = {0, 0, 0, 0};
    for (int it = 0; it < 64; ++it) {
        int pos = wbase + it * 2 + half;
        if (wbase + it * 2 >= pend) break;    // both halves done
        if (pos >= pend) continue;            // boundary half
        int idx = pos - p0;
        const float* vrow;
        if (pos == L - 1) {
            vrow = newvrow;
        } else {
            int bid = bts[idx >> 4];
            vrow = vcache + (size_t)((bid * BLKSZ + (pos & 15)) * NKVH + kvh) * HDIM;
        }
        float4 v4 = *(const float4*)(vrow + l32 * 4);
        float w0 = sc[0][idx], w1 = sc[1][idx], w2 = sc[2][idx], w3 = sc[3][idx];
        a0.x += w0 * v4.x; a0.y += w0 * v4.y; a0.z += w0 * v4.z; a0.w += w0 * v4.w;
        a1.x += w1 * v4.x; a1.y += w1 * v4.y; a1.z += w1 * v4.z; a1.w += w1 * v4.w;
        a2.x += w2 * v4.x; a2.y += w2 * v4.y; a2.z += w2 * v4.z; a2.w += w2 * v4.w;
        a3.x += w3 * v4.x; a3.y += w3 * v4.y; a3.z += w3 * v4.z; a3.w += w3 * v4.w;
    }
    // fold the two halves (even/odd positions) together
    a0.x += __shfl_xor(a0.x, 32, 64); a0.y += __shfl_xor(a0.y, 32, 64);
    a0.z += __shfl_xor(a0.z, 32, 64); a0.w += __shfl_xor(a0.w, 32, 64);
    a1.x += __shfl_xor(a1.x, 32, 64); a1.y += __shfl_xor(a1.y, 32, 64);
    a1.z += __shfl_xor(a1.z, 32, 64); a1.w += __shfl_xor(a1.w, 32, 64);
    a2.x += __shfl_xor(a2.x, 32, 64); a2.y += __shfl_xor(a2.y, 32, 64);
    a2.z += __shfl_xor(a2.z, 32, 64); a2.w += __shfl_xor(a2.w, 32, 64);
    a3.x += __shfl_xor(a3.x, 32, 64); a3.y += __shfl_xor(a3.y, 32, 64);
    a3.z += __shfl_xor(a3.z, 32, 64); a3.w += __shfl_xor(a3.w, 32, 64);

    if (half == 0) {
        *(float4*)&red[wave][0][l32 * 4] = a0;
        *(float4*)&red[wave][1][l32 * 4] = a1;
        *(float4*)&red[wave][2][l32 * 4] = a2;
        *(float4*)&red[wave][3][l32 * 4] = a3;
    }
    __syncthreads();

    for (int idx = tid; idx < NGRP * HDIM; idx += 256) {
        int g = idx >> 7, d = idx & (HDIM - 1);
        float o = red[0][g][d] + red[1][g][d] + red[2][g][d] + red[3][g][d];
        pO[((size_t)((b * NKVH + kvh) * NGRP + g) * NCHUNK + c) * HDIM + d] = o;
    }
}

// ---------------------------------------------------------------------------
// Kernel 2: combine the NCHUNK partials per (b, kvh, g) with log-sum-exp.
// Grid = B*HKV*G blocks of 128 threads (one thread per output dim).
// ---------------------------------------------------------------------------
__global__ __launch_bounds__(128) void attn_reduce(
    const float* __restrict__ pO,
    const float* __restrict__ pM,
    const float* __restrict__ pL,
    const int*   __restrict__ seq_lens,
    float* __restrict__ out)
{
    const int bid = blockIdx.x;              // == ((b*NKVH+kvh)*NGRP+g)
    const int g   = bid & (NGRP - 1);
    const int kvh = (bid >> 2) & (NKVH - 1);
    const int b   = bid >> 5;
    const int d   = threadIdx.x;

    const int L  = seq_lens[b];
    const int nc = (L + CHUNK - 1) / CHUNK;
    const int base = bid * NCHUNK;

    float m = -1e30f;
    for (int c = 0; c < nc; ++c) m = fmaxf(m, pM[base + c]);
    float l = 0.f, o = 0.f;
    for (int c = 0; c < nc; ++c) {
        float w = __expf(pM[base + c] - m);
        l += pL[base + c] * w;
        o += pO[(size_t)(base + c) * HDIM + d] * w;
    }
    out[(size_t)b * NHEAD * HDIM + (g * NKVH + kvh) * HDIM + d] = o / l;
}

extern "C" void kernel_launch(void* const* d_in, const int* in_sizes, int n_in,
                              void* d_out, int out_size, void* d_ws, size_t ws_size,
                              hipStream_t stream) {
    const float* q     = (const float*)d_in[0];
    const float* knew  = (const float*)d_in[1];
    const float* vnew  = (const float*)d_in[2];
    const float* cache = (const float*)d_in[3];
    const int*   btab  = (const int*)d_in[4];
    // d_in[5] slot_mapping: implied by seq_lens + block_tables (substituted in-kernel)
    const int*   seq   = (const int*)d_in[6];
    // d_in[7] is_prefill: always 0 for this problem
    float* out = (float*)d_out;

    // workspace layout: pO | pM | pL  (~4.25 MB total)
    float* pO = (float*)d_ws;
    float* pM = pO + (size_t)BATCH * NKVH * NGRP * NCHUNK * HDIM;
    float* pL = pM + (size_t)BATCH * NKVH * NGRP * NCHUNK;

    attn_partial<<<dim3(NCHUNK, NKVH, BATCH), 256, 0, stream>>>(
        q, knew, vnew, cache, btab, seq, pO, pM, pL);
    attn_reduce<<<dim3(BATCH * NKVH * NGRP), 128, 0, stream>>>(
        pO, pM, pL, seq, out);
}